// Round 1
// baseline (1470.149 us; speedup 1.0000x reference)
//
#include <hip/hip_runtime.h>

#define THREADS 256

// ---------------- CSR build ----------------

__global__ void zero_kernel(int* __restrict__ p, int n) {
    int i = blockIdx.x * blockDim.x + threadIdx.x;
    if (i < n) p[i] = 0;
}

__global__ void hist_kernel(const int* __restrict__ row, int* __restrict__ cnt, int n) {
    int stride = gridDim.x * blockDim.x;
    for (int e = blockIdx.x * blockDim.x + threadIdx.x; e < n; e += stride)
        atomicAdd(&cnt[row[e]], 1);
}

// Single-block chunked Hillis-Steele exclusive scan over n counts.
// Writes offs[0..n] (exclusive prefix, offs[n]=total) and cur[0..n-1]=offs[i].
__global__ void scan_kernel(const int* __restrict__ cnt, int* __restrict__ offs,
                            int* __restrict__ cur, int n) {
    __shared__ int buf[2][THREADS];
    __shared__ int running_s;
    int tid = threadIdx.x;
    if (tid == 0) running_s = 0;
    __syncthreads();
    for (int base = 0; base < n; base += THREADS) {
        int idx = base + tid;
        int v = (idx < n) ? cnt[idx] : 0;
        int incl = v;
        int cb = 0;
        buf[0][tid] = incl;
        __syncthreads();
        #pragma unroll
        for (int off = 1; off < THREADS; off <<= 1) {
            int t = incl;
            if (tid >= off) t += buf[cb][tid - off];
            cb ^= 1;
            buf[cb][tid] = t;
            incl = t;
            __syncthreads();
        }
        int base_run = running_s;
        if (idx < n) {
            int excl = base_run + incl - v;
            offs[idx] = excl;
            cur[idx] = excl;
        }
        int total = buf[cb][THREADS - 1];
        __syncthreads();
        if (tid == 0) running_s = base_run + total;
        __syncthreads();
    }
    if (tid == 0) offs[n] = running_s;
}

__global__ void place_kernel(const int* __restrict__ row, const int* __restrict__ col,
                             const float* __restrict__ val, int* __restrict__ cur,
                             int* __restrict__ ccol, float* __restrict__ cval, int n) {
    int stride = gridDim.x * blockDim.x;
    for (int e = blockIdx.x * blockDim.x + threadIdx.x; e < n; e += stride) {
        int r = row[e];
        int p = atomicAdd(&cur[r], 1);
        ccol[p] = col[e];
        cval[p] = val[e];
    }
}

// ---------------- SpMM: one wave64 per node ----------------
// Each lane owns one float4 (64 lanes x 16B = 256 floats = one feature row).
// agg row written to out (d_out serves as agg buffer).
__global__ void spmm_kernel(const float4* __restrict__ x4, const int* __restrict__ offs,
                            const int* __restrict__ ccol, const float* __restrict__ cval,
                            float4* __restrict__ out4, int nnodes) {
    int wid = (blockIdx.x * blockDim.x + threadIdx.x) >> 6;
    int lane = threadIdx.x & 63;
    if (wid >= nnodes) return;
    int s = offs[wid];
    int e = offs[wid + 1];
    float4 acc = make_float4(0.f, 0.f, 0.f, 0.f);
    for (int i = s; i < e; ++i) {
        int c = ccol[i];
        float v = cval[i];
        float4 xv = x4[(size_t)c * 64 + lane];
        acc.x = fmaf(v, xv.x, acc.x);
        acc.y = fmaf(v, xv.y, acc.y);
        acc.z = fmaf(v, xv.z, acc.z);
        acc.w = fmaf(v, xv.w, acc.w);
    }
    out4[(size_t)wid * 64 + lane] = acc;
}

// ---------------- In-place GEMM: out = agg @ W^T + b ----------------
// Each block owns a disjoint 64-row band of `out`. It loads the whole band
// (64x256 f32) into LDS FIRST, then computes and overwrites the band.
// In-place is safe: blocks only read/write their own band.
__launch_bounds__(256, 2)
__global__ void gemm_kernel(float* __restrict__ out, const float* __restrict__ W,
                            const float* __restrict__ b, int nrows) {
    __shared__ float As[64][260];  // pad 260 (mult of 4 -> float4 stores OK; 2-way bank max)
    __shared__ float Bs[64][33];   // pad 33 -> conflict-free reads Bs[tc*4+j][kk]
    int tid = threadIdx.x;
    int rowBase = blockIdx.x * 64;

    const float4* out4c = reinterpret_cast<const float4*>(out);
    for (int i = tid; i < 64 * 64; i += 256) {
        int r = i >> 6, c4 = i & 63;
        int gr = rowBase + r;
        float4 v = make_float4(0.f, 0.f, 0.f, 0.f);
        if (gr < nrows) v = out4c[(size_t)gr * 64 + c4];
        *reinterpret_cast<float4*>(&As[r][c4 * 4]) = v;
    }
    __syncthreads();

    int tr = tid >> 4, tc = tid & 15;
    const float4* W4 = reinterpret_cast<const float4*>(W);

    for (int colTile = 0; colTile < 256; colTile += 64) {
        float acc[4][4] = {};
        for (int k0 = 0; k0 < 256; k0 += 32) {
            // stage W tile: rows colTile..+63 (output features), cols k0..+31
            for (int i = tid; i < 64 * 8; i += 256) {
                int r = i >> 3, c4 = i & 7;
                float4 wv = W4[(((size_t)(colTile + r)) << 6) + (k0 >> 2) + c4];
                Bs[r][c4 * 4 + 0] = wv.x;
                Bs[r][c4 * 4 + 1] = wv.y;
                Bs[r][c4 * 4 + 2] = wv.z;
                Bs[r][c4 * 4 + 3] = wv.w;
            }
            __syncthreads();
            #pragma unroll
            for (int kk = 0; kk < 32; ++kk) {
                float a[4], wv[4];
                #pragma unroll
                for (int i2 = 0; i2 < 4; ++i2) a[i2] = As[tr * 4 + i2][k0 + kk];
                #pragma unroll
                for (int j = 0; j < 4; ++j) wv[j] = Bs[tc * 4 + j][kk];
                #pragma unroll
                for (int i2 = 0; i2 < 4; ++i2)
                    #pragma unroll
                    for (int j = 0; j < 4; ++j)
                        acc[i2][j] = fmaf(a[i2], wv[j], acc[i2][j]);
            }
            __syncthreads();
        }
        // epilogue: bias + write back into the band (global only; LDS As untouched)
        #pragma unroll
        for (int i2 = 0; i2 < 4; ++i2) {
            int gr = rowBase + tr * 4 + i2;
            if (gr < nrows) {
                int gc = colTile + tc * 4;
                float4 o;
                o.x = acc[i2][0] + b[gc + 0];
                o.y = acc[i2][1] + b[gc + 1];
                o.z = acc[i2][2] + b[gc + 2];
                o.w = acc[i2][3] + b[gc + 3];
                reinterpret_cast<float4*>(out)[(size_t)gr * 64 + (gc >> 2)] = o;
            }
        }
    }
}

// ---------------- launch ----------------

extern "C" void kernel_launch(void* const* d_in, const int* in_sizes, int n_in,
                              void* d_out, int out_size, void* d_ws, size_t ws_size,
                              hipStream_t stream) {
    const float* x     = (const float*)d_in[0];
    const int*   erow  = (const int*)d_in[1];
    const int*   ecol  = (const int*)d_in[2];
    const float* evalv = (const float*)d_in[3];
    const float* W     = (const float*)d_in[4];
    const float* b     = (const float*)d_in[5];
    float* out = (float*)d_out;

    int n_nodes = in_sizes[0] / 256;
    int n_edges = in_sizes[1];

    // workspace layout (all int/float = 4B), 64-element aligned chunks
    int* cnt  = (int*)d_ws;
    int* offs = cnt  + ((n_nodes + 63) & ~63);
    int* cur  = offs + ((n_nodes + 1 + 63) & ~63);
    int* ccol = cur  + ((n_nodes + 63) & ~63);
    float* cval = (float*)(ccol + ((n_edges + 63) & ~63));

    zero_kernel<<<(n_nodes + THREADS - 1) / THREADS, THREADS, 0, stream>>>(cnt, n_nodes);
    hist_kernel<<<1024, THREADS, 0, stream>>>(erow, cnt, n_edges);
    scan_kernel<<<1, THREADS, 0, stream>>>(cnt, offs, cur, n_nodes);
    place_kernel<<<1024, THREADS, 0, stream>>>(erow, ecol, evalv, cur, ccol, cval, n_edges);

    int spmm_blocks = (n_nodes + 3) / 4;  // 4 waves per block, 1 wave per node
    spmm_kernel<<<spmm_blocks, THREADS, 0, stream>>>(
        (const float4*)x, offs, ccol, cval, (float4*)out, n_nodes);

    int gemm_blocks = (n_nodes + 63) / 64;
    gemm_kernel<<<gemm_blocks, THREADS, 0, stream>>>(out, W, b, n_nodes);
}

// Round 2
// 646.070 us; speedup vs baseline: 2.2755x; 2.2755x over previous
//
#include <hip/hip_runtime.h>

#define THREADS 256

typedef __attribute__((ext_vector_type(8))) short short8;
typedef __attribute__((ext_vector_type(4))) float f32x4;

__device__ __forceinline__ unsigned short f2bf(float f) {
    unsigned u = __builtin_bit_cast(unsigned, f);
    unsigned r = (u + 0x7FFFu + ((u >> 16) & 1u)) >> 16;  // RNE
    return (unsigned short)r;
}
__device__ __forceinline__ float bf2f_lo(unsigned u) {
    return __builtin_bit_cast(float, u << 16);
}
__device__ __forceinline__ float bf2f_hi(unsigned u) {
    return __builtin_bit_cast(float, u & 0xFFFF0000u);
}

// ---------------- CSR build ----------------

__global__ void zero_kernel(int* __restrict__ p, int n) {
    int i = blockIdx.x * blockDim.x + threadIdx.x;
    if (i < n) p[i] = 0;
}

__global__ void hist_kernel(const int* __restrict__ row, int* __restrict__ cnt, int n) {
    int stride = gridDim.x * blockDim.x;
    for (int e = blockIdx.x * blockDim.x + threadIdx.x; e < n; e += stride)
        atomicAdd(&cnt[row[e]], 1);
}

// scan1: per-block (1024 elems) exclusive scan into offs, block sums into bsum
__global__ void scan1_kernel(const int* __restrict__ cnt, int* __restrict__ offs,
                             int* __restrict__ bsum, int n) {
    int tid = threadIdx.x;
    int base = blockIdx.x * 1024 + tid * 4;
    int v0 = 0, v1 = 0, v2 = 0, v3 = 0;
    if (base + 3 < n) {
        int4 v = *reinterpret_cast<const int4*>(cnt + base);
        v0 = v.x; v1 = v.y; v2 = v.z; v3 = v.w;
    } else {
        if (base + 0 < n) v0 = cnt[base + 0];
        if (base + 1 < n) v1 = cnt[base + 1];
        if (base + 2 < n) v2 = cnt[base + 2];
    }
    int ts = v0 + v1 + v2 + v3;
    int lane = tid & 63;
    int incl = ts;
    #pragma unroll
    for (int off = 1; off < 64; off <<= 1) {
        int t = __shfl_up(incl, off, 64);
        if (lane >= off) incl += t;
    }
    __shared__ int wsum[4];
    int w = tid >> 6;
    if (lane == 63) wsum[w] = incl;
    __syncthreads();
    int wo = 0;
    for (int i = 0; i < w; ++i) wo += wsum[i];
    int excl = wo + incl - ts;
    if (base + 0 < n) offs[base + 0] = excl;
    if (base + 1 < n) offs[base + 1] = excl + v0;
    if (base + 2 < n) offs[base + 2] = excl + v0 + v1;
    if (base + 3 < n) offs[base + 3] = excl + v0 + v1 + v2;
    if (tid == THREADS - 1) bsum[blockIdx.x] = wo + incl;
}

// scan2: single block, exclusive scan of bsum[0..nb), total -> bsum[nb]
__global__ void scan2_kernel(int* __restrict__ bsum, int nb) {
    int tid = threadIdx.x;
    int base = tid * 4;
    int v0 = 0, v1 = 0, v2 = 0, v3 = 0;
    if (base + 0 < nb) v0 = bsum[base + 0];
    if (base + 1 < nb) v1 = bsum[base + 1];
    if (base + 2 < nb) v2 = bsum[base + 2];
    if (base + 3 < nb) v3 = bsum[base + 3];
    int ts = v0 + v1 + v2 + v3;
    int lane = tid & 63;
    int incl = ts;
    #pragma unroll
    for (int off = 1; off < 64; off <<= 1) {
        int t = __shfl_up(incl, off, 64);
        if (lane >= off) incl += t;
    }
    __shared__ int wsum[4];
    int w = tid >> 6;
    if (lane == 63) wsum[w] = incl;
    __syncthreads();
    int wo = 0;
    for (int i = 0; i < w; ++i) wo += wsum[i];
    int excl = wo + incl - ts;
    if (base + 0 < nb) bsum[base + 0] = excl;
    if (base + 1 < nb) bsum[base + 1] = excl + v0;
    if (base + 2 < nb) bsum[base + 2] = excl + v0 + v1;
    if (base + 3 < nb) bsum[base + 3] = excl + v0 + v1 + v2;
    if (tid == THREADS - 1) bsum[nb] = wo + incl;
}

// scan3: offs[i] += bsum[i>>10]; cur[i] = offs[i]; offs[n] = total
__global__ void scan3_kernel(int* __restrict__ offs, const int* __restrict__ bsum,
                             int* __restrict__ cur, int n) {
    int i = blockIdx.x * blockDim.x + threadIdx.x;
    if (i < n) {
        int v = offs[i] + bsum[i >> 10];
        offs[i] = v;
        cur[i] = v;
    }
    if (i == 0) offs[n] = bsum[(n + 1023) >> 10];
}

__global__ void place_kernel(const int* __restrict__ row, const int* __restrict__ col,
                             const float* __restrict__ val, int* __restrict__ cur,
                             int2* __restrict__ pr, int n) {
    int stride = gridDim.x * blockDim.x;
    for (int e = blockIdx.x * blockDim.x + threadIdx.x; e < n; e += stride) {
        int r = row[e];
        int p = atomicAdd(&cur[r], 1);
        pr[p] = make_int2(col[e], __float_as_int(val[e]));
    }
}

// ---------------- dtype converts ----------------

// 8 f32 -> 8 bf16 per thread
__global__ void cvt_bf16_kernel(const float4* __restrict__ in, uint4* __restrict__ out, int n8) {
    int i = blockIdx.x * blockDim.x + threadIdx.x;
    if (i >= n8) return;
    float4 a = in[2 * i], b = in[2 * i + 1];
    uint4 o;
    o.x = (unsigned)f2bf(a.x) | ((unsigned)f2bf(a.y) << 16);
    o.y = (unsigned)f2bf(a.z) | ((unsigned)f2bf(a.w) << 16);
    o.z = (unsigned)f2bf(b.x) | ((unsigned)f2bf(b.y) << 16);
    o.w = (unsigned)f2bf(b.z) | ((unsigned)f2bf(b.w) << 16);
    out[i] = o;
}

// ---------------- SpMM variants: one wave64 per node ----------------

// bf16 gather: lane owns features [4*lane .. 4*lane+3]; row = 64 x uint2 (8B)
__global__ void spmm_bf16_kernel(const uint2* __restrict__ xb, const int* __restrict__ offs,
                                 const int2* __restrict__ pr, float4* __restrict__ out4,
                                 int nnodes) {
    int wid = (blockIdx.x * blockDim.x + threadIdx.x) >> 6;
    int lane = threadIdx.x & 63;
    if (wid >= nnodes) return;
    int s = offs[wid], e = offs[wid + 1];
    float a0 = 0.f, a1 = 0.f, a2 = 0.f, a3 = 0.f;
    int i = s;
    if (i < e && (i & 1)) {  // align to even for int4 pair loads
        int2 p = pr[i];
        uint2 xv = xb[(size_t)p.x * 64 + lane];
        float v = __int_as_float(p.y);
        a0 = fmaf(v, bf2f_lo(xv.x), a0);
        a1 = fmaf(v, bf2f_hi(xv.x), a1);
        a2 = fmaf(v, bf2f_lo(xv.y), a2);
        a3 = fmaf(v, bf2f_hi(xv.y), a3);
        ++i;
    }
    for (; i + 4 <= e; i += 4) {
        int4 pa = *reinterpret_cast<const int4*>(pr + i);
        int4 pb = *reinterpret_cast<const int4*>(pr + i + 2);
        uint2 x0 = xb[(size_t)pa.x * 64 + lane];
        uint2 x1 = xb[(size_t)pa.z * 64 + lane];
        uint2 x2 = xb[(size_t)pb.x * 64 + lane];
        uint2 x3 = xb[(size_t)pb.z * 64 + lane];
        float v0 = __int_as_float(pa.y), v1 = __int_as_float(pa.w);
        float v2 = __int_as_float(pb.y), v3 = __int_as_float(pb.w);
        a0 = fmaf(v0, bf2f_lo(x0.x), a0); a1 = fmaf(v0, bf2f_hi(x0.x), a1);
        a2 = fmaf(v0, bf2f_lo(x0.y), a2); a3 = fmaf(v0, bf2f_hi(x0.y), a3);
        a0 = fmaf(v1, bf2f_lo(x1.x), a0); a1 = fmaf(v1, bf2f_hi(x1.x), a1);
        a2 = fmaf(v1, bf2f_lo(x1.y), a2); a3 = fmaf(v1, bf2f_hi(x1.y), a3);
        a0 = fmaf(v2, bf2f_lo(x2.x), a0); a1 = fmaf(v2, bf2f_hi(x2.x), a1);
        a2 = fmaf(v2, bf2f_lo(x2.y), a2); a3 = fmaf(v2, bf2f_hi(x2.y), a3);
        a0 = fmaf(v3, bf2f_lo(x3.x), a0); a1 = fmaf(v3, bf2f_hi(x3.x), a1);
        a2 = fmaf(v3, bf2f_lo(x3.y), a2); a3 = fmaf(v3, bf2f_hi(x3.y), a3);
    }
    for (; i < e; ++i) {
        int2 p = pr[i];
        uint2 xv = xb[(size_t)p.x * 64 + lane];
        float v = __int_as_float(p.y);
        a0 = fmaf(v, bf2f_lo(xv.x), a0);
        a1 = fmaf(v, bf2f_hi(xv.x), a1);
        a2 = fmaf(v, bf2f_lo(xv.y), a2);
        a3 = fmaf(v, bf2f_hi(xv.y), a3);
    }
    out4[(size_t)wid * 64 + lane] = make_float4(a0, a1, a2, a3);
}

// f32 fallback (small ws): lane owns one float4
__global__ void spmm_f32_kernel(const float4* __restrict__ x4, const int* __restrict__ offs,
                                const int2* __restrict__ pr, float4* __restrict__ out4,
                                int nnodes) {
    int wid = (blockIdx.x * blockDim.x + threadIdx.x) >> 6;
    int lane = threadIdx.x & 63;
    if (wid >= nnodes) return;
    int s = offs[wid], e = offs[wid + 1];
    float4 acc = make_float4(0.f, 0.f, 0.f, 0.f);
    int i = s;
    if (i < e && (i & 1)) {
        int2 p = pr[i];
        float4 xv = x4[(size_t)p.x * 64 + lane];
        float v = __int_as_float(p.y);
        acc.x = fmaf(v, xv.x, acc.x); acc.y = fmaf(v, xv.y, acc.y);
        acc.z = fmaf(v, xv.z, acc.z); acc.w = fmaf(v, xv.w, acc.w);
        ++i;
    }
    for (; i + 4 <= e; i += 4) {
        int4 pa = *reinterpret_cast<const int4*>(pr + i);
        int4 pb = *reinterpret_cast<const int4*>(pr + i + 2);
        float4 x0 = x4[(size_t)pa.x * 64 + lane];
        float4 x1 = x4[(size_t)pa.z * 64 + lane];
        float4 x2 = x4[(size_t)pb.x * 64 + lane];
        float4 x3 = x4[(size_t)pb.z * 64 + lane];
        float v0 = __int_as_float(pa.y), v1 = __int_as_float(pa.w);
        float v2 = __int_as_float(pb.y), v3 = __int_as_float(pb.w);
        acc.x = fmaf(v0, x0.x, acc.x); acc.y = fmaf(v0, x0.y, acc.y);
        acc.z = fmaf(v0, x0.z, acc.z); acc.w = fmaf(v0, x0.w, acc.w);
        acc.x = fmaf(v1, x1.x, acc.x); acc.y = fmaf(v1, x1.y, acc.y);
        acc.z = fmaf(v1, x1.z, acc.z); acc.w = fmaf(v1, x1.w, acc.w);
        acc.x = fmaf(v2, x2.x, acc.x); acc.y = fmaf(v2, x2.y, acc.y);
        acc.z = fmaf(v2, x2.z, acc.z); acc.w = fmaf(v2, x2.w, acc.w);
        acc.x = fmaf(v3, x3.x, acc.x); acc.y = fmaf(v3, x3.y, acc.y);
        acc.z = fmaf(v3, x3.z, acc.z); acc.w = fmaf(v3, x3.w, acc.w);
    }
    for (; i < e; ++i) {
        int2 p = pr[i];
        float4 xv = x4[(size_t)p.x * 64 + lane];
        float v = __int_as_float(p.y);
        acc.x = fmaf(v, xv.x, acc.x); acc.y = fmaf(v, xv.y, acc.y);
        acc.z = fmaf(v, xv.z, acc.z); acc.w = fmaf(v, xv.w, acc.w);
    }
    out4[(size_t)wid * 64 + lane] = acc;
}

// ---------------- In-place MFMA GEMM: out = agg @ W^T + b ----------------
// Block owns a disjoint 64-row band; stages band (f32->bf16) into LDS first,
// then MFMA against bf16 W; in-place safe.
__launch_bounds__(256, 2)
__global__ void gemm_mfma_kernel(float* __restrict__ out, const unsigned short* __restrict__ Wb,
                                 const float* __restrict__ bias, int nrows) {
    __shared__ unsigned short As[64][264];  // 256 + 8 pad
    __shared__ unsigned short Ws[256][40];  // 32 + 8 pad (one k-slice)
    int tid = threadIdx.x;
    int rowBase = blockIdx.x * 64;

    const float4* o4 = reinterpret_cast<const float4*>(out);
    for (int it = tid; it < 64 * 64; it += 256) {
        int r = it >> 6, c = it & 63;
        float4 v = make_float4(0.f, 0.f, 0.f, 0.f);
        int gr = rowBase + r;
        if (gr < nrows) v = o4[(size_t)gr * 64 + c];
        ushort4 w;
        w.x = f2bf(v.x); w.y = f2bf(v.y); w.z = f2bf(v.z); w.w = f2bf(v.w);
        *reinterpret_cast<ushort4*>(&As[r][c * 4]) = w;
    }

    int w = tid >> 6, lane = tid & 63;
    int lr = lane & 15, lg = lane >> 4;
    f32x4 acc[16];
    #pragma unroll
    for (int nt = 0; nt < 16; ++nt) acc[nt] = (f32x4){0.f, 0.f, 0.f, 0.f};

    for (int k0 = 0; k0 < 256; k0 += 32) {
        __syncthreads();  // band staged (1st iter) / prior Ws reads done
        for (int it = tid; it < 1024; it += 256) {
            int r = it >> 2, c = it & 3;  // c-th 16B chunk (8 bf16)
            uint4 v = *reinterpret_cast<const uint4*>(Wb + (size_t)r * 256 + k0 + c * 8);
            *reinterpret_cast<uint4*>(&Ws[r][c * 8]) = v;
        }
        __syncthreads();
        short8 af = *reinterpret_cast<const short8*>(&As[w * 16 + lr][k0 + 8 * lg]);
        #pragma unroll
        for (int nt = 0; nt < 16; ++nt) {
            short8 bf_ = *reinterpret_cast<const short8*>(&Ws[nt * 16 + lr][8 * lg]);
            acc[nt] = __builtin_amdgcn_mfma_f32_16x16x32_bf16(af, bf_, acc[nt], 0, 0, 0);
        }
    }

    #pragma unroll
    for (int nt = 0; nt < 16; ++nt) {
        int gc = nt * 16 + lr;
        float bv = bias[gc];
        #pragma unroll
        for (int q = 0; q < 4; ++q) {
            int gr = rowBase + w * 16 + lg * 4 + q;
            if (gr < nrows) out[(size_t)gr * 256 + gc] = acc[nt][q] + bv;
        }
    }
}

// ---------------- launch ----------------

extern "C" void kernel_launch(void* const* d_in, const int* in_sizes, int n_in,
                              void* d_out, int out_size, void* d_ws, size_t ws_size,
                              hipStream_t stream) {
    const float* x     = (const float*)d_in[0];
    const int*   erow  = (const int*)d_in[1];
    const int*   ecol  = (const int*)d_in[2];
    const float* evalv = (const float*)d_in[3];
    const float* W     = (const float*)d_in[4];
    const float* bias  = (const float*)d_in[5];
    float* out = (float*)d_out;

    int n_nodes = in_sizes[0] / 256;
    int n_edges = in_sizes[1];
    int nb = (n_nodes + 1023) >> 10;  // scan blocks

    // workspace layout (units: int = 4B)
    size_t A = (size_t)((n_nodes + 63) & ~63);
    int* cnt   = (int*)d_ws;
    int* offs  = cnt + A;                 // needs n_nodes+1 <= A
    int* cur   = offs + A;
    int* bsum  = cur + A;                 // nb+1 ints
    int* wbase = bsum + (((size_t)nb + 64) & ~63ull);
    unsigned short* Wb = (unsigned short*)wbase;            // 256*256 bf16
    int2* pr   = (int2*)(wbase + 32768);                    // n_edges int2
    unsigned short* xb = (unsigned short*)(pr + n_edges);   // n_nodes*256 bf16
    size_t need_bf16 = (size_t)((char*)(xb + (size_t)n_nodes * 256) - (char*)d_ws);
    bool use_bf16 = ws_size >= need_bf16;

    zero_kernel<<<(n_nodes + THREADS - 1) / THREADS, THREADS, 0, stream>>>(cnt, n_nodes);
    hist_kernel<<<1024, THREADS, 0, stream>>>(erow, cnt, n_edges);
    scan1_kernel<<<nb, THREADS, 0, stream>>>(cnt, offs, bsum, n_nodes);
    scan2_kernel<<<1, THREADS, 0, stream>>>(bsum, nb);
    scan3_kernel<<<(n_nodes + THREADS - 1) / THREADS, THREADS, 0, stream>>>(offs, bsum, cur, n_nodes);
    place_kernel<<<1024, THREADS, 0, stream>>>(erow, ecol, evalv, cur, pr, n_edges);

    // W -> bf16 (65536 elems / 8 per thread)
    cvt_bf16_kernel<<<(65536 / 8 + THREADS - 1) / THREADS, THREADS, 0, stream>>>(
        (const float4*)W, (uint4*)Wb, 65536 / 8);

    int spmm_blocks = (n_nodes + 3) / 4;  // 4 waves/block, 1 wave/node
    if (use_bf16) {
        int n8 = n_nodes * 32;  // n_nodes*256/8
        cvt_bf16_kernel<<<(n8 + THREADS - 1) / THREADS, THREADS, 0, stream>>>(
            (const float4*)x, (uint4*)xb, n8);
        spmm_bf16_kernel<<<spmm_blocks, THREADS, 0, stream>>>(
            (const uint2*)xb, offs, pr, (float4*)out, n_nodes);
    } else {
        spmm_f32_kernel<<<spmm_blocks, THREADS, 0, stream>>>(
            (const float4*)x, offs, pr, (float4*)out, n_nodes);
    }

    int gemm_blocks = (n_nodes + 63) / 64;
    gemm_mfma_kernel<<<gemm_blocks, THREADS, 0, stream>>>(out, Wb, bias, n_nodes);
}